// Round 11
// baseline (192.103 us; speedup 1.0000x reference)
//
#include <hip/hip_runtime.h>
#include <hip/hip_bf16.h>
#include <math.h>

typedef __attribute__((ext_vector_type(8))) short bf16x8;
typedef __attribute__((ext_vector_type(4))) float f32x4;
typedef __attribute__((ext_vector_type(4))) unsigned short u16x4;

__device__ __forceinline__ float leaky(float x) { return x > 0.0f ? x : 0.01f * x; }

__device__ __forceinline__ unsigned short f2b(float f) {
    unsigned u = __builtin_bit_cast(unsigned, f);
    u += 0x7fffu + ((u >> 16) & 1u);
    return (unsigned short)(u >> 16);
}

__device__ __forceinline__ bf16x8 cvt8(float4 u0, float4 u1) {
    bf16x8 r;
    r[0] = (short)f2b(u0.x); r[1] = (short)f2b(u0.y);
    r[2] = (short)f2b(u0.z); r[3] = (short)f2b(u0.w);
    r[4] = (short)f2b(u1.x); r[5] = (short)f2b(u1.y);
    r[6] = (short)f2b(u1.z); r[7] = (short)f2b(u1.w);
    return r;
}

// ================= D1: LDS-staged Wfuse + both HW means + zero =================
// blk [0,64):        Ws1[1024,512] = sw1 @ wsh  (16 m-tiles of 64 x 4 n-tiles of 128)
// blk [64,16448):    x_mid mean -> xm_b
// blk [16448,32832): x_deep mean -> xd_b
// blk [32832,33217): zero wf[0..394240)
__global__ __launch_bounds__(256) void prep_kernel(
    const float* __restrict__ xm, const float* __restrict__ xd,
    const float* __restrict__ sw1, const float* __restrict__ wsh,
    unsigned short* __restrict__ Ws1,
    unsigned short* __restrict__ xm_b, unsigned short* __restrict__ xd_b,
    float4* __restrict__ zbase)
{
    const int blk = blockIdx.x;
    const int tid = threadIdx.x;

    if (blk < 64) {
        // Wfuse: Ws1[m,n] = sum_k sw1[m,k]*wsh[k,n].  wsh is [K,N] row-major ->
        // stage 32k x 128n panel transposed to LDS (coalesced reads, bf16x8 frag reads).
        __shared__ unsigned short BsT[128][40];    // [n][k], stride 40 (80B, 16B-aligned)
        const int mb = blk >> 2, nb = blk & 3;
        const int l = tid & 63, lr = l & 15, lc = l >> 4, w = tid >> 6;
        const int m0 = mb * 64 + w * 16;
        const int n0 = nb * 128;
        const float* ap = sw1 + (size_t)(m0 + lr) * 2048 + lc * 8;
        f32x4 acc[4][2];
        #pragma unroll
        for (int nf = 0; nf < 4; ++nf)
            #pragma unroll
            for (int p = 0; p < 2; ++p) acc[nf][p] = (f32x4){0.f,0.f,0.f,0.f};

        for (int kt = 0; kt < 2048; kt += 32) {
            __syncthreads();                       // prev-iter BsT reads done
            #pragma unroll
            for (int it = 0; it < 4; ++it) {
                int idx = it * 256 + tid;          // 0..1023
                int r = idx >> 5;                  // k row 0..31
                int q = idx & 31;                  // n quad 0..31
                float4 v = *(const float4*)(wsh + (size_t)(kt + r) * 512 + n0 + q * 4);
                BsT[q * 4 + 0][r] = f2b(v.x);
                BsT[q * 4 + 1][r] = f2b(v.y);
                BsT[q * 4 + 2][r] = f2b(v.z);
                BsT[q * 4 + 3][r] = f2b(v.w);
            }
            __syncthreads();

            bf16x8 a = cvt8(*(const float4*)(ap + kt), *(const float4*)(ap + kt + 4));
            #pragma unroll
            for (int nf = 0; nf < 4; ++nf)
                #pragma unroll
                for (int p = 0; p < 2; ++p) {
                    bf16x8 b = *(const bf16x8*)&BsT[nf * 32 + p * 16 + lr][lc * 8];
                    acc[nf][p] = __builtin_amdgcn_mfma_f32_16x16x32_bf16(a, b, acc[nf][p], 0, 0, 0);
                }
        }
        #pragma unroll
        for (int nf = 0; nf < 4; ++nf)
            #pragma unroll
            for (int p = 0; p < 2; ++p)
                #pragma unroll
                for (int r = 0; r < 4; ++r) {
                    int m = m0 + lc * 4 + r;
                    int n = n0 + nf * 32 + p * 16 + lr;
                    Ws1[(size_t)m * 512 + n] = f2b(acc[nf][p][r]);
                }
        return;
    }
    if (blk < 16448) {
        int b2 = blk - 64;
        int lane = tid & 63, wid = tid >> 6;
        int row  = b2 * 4 + wid;
        const float4* r = (const float4*)(xm + (size_t)row * 784);
        float s = 0.0f;
        for (int i = lane; i < 196; i += 64) {
            float4 v = r[i];
            s += v.x + v.y + v.z + v.w;
        }
        #pragma unroll
        for (int off = 32; off; off >>= 1) s += __shfl_xor(s, off);
        if (lane == 0) xm_b[row] = f2b(s * (1.0f / 784.0f));
        return;
    }
    if (blk < 32832) {
        int b3 = blk - 16448;
        int sub = tid & 15, rr = tid >> 4;
        int row = b3 * 16 + rr;
        const float* base = xd + (size_t)row * 49;
        float s = base[sub] + base[sub + 16] + base[sub + 32];
        if (sub == 0) s += base[48];
        #pragma unroll
        for (int off = 8; off; off >>= 1) s += __shfl_xor(s, off);
        if (sub == 0) xd_b[row] = f2b(s * (1.0f / 49.0f));
        return;
    }
    {
        int idx = (blk - 32832) * 256 + tid;       // 385*256 = 98560 float4 = 394240 floats
        zbase[idx] = make_float4(0.f, 0.f, 0.f, 0.f);
    }
}

// ---------- gate: poll write-once FLAG (relaxed LLC load + backoff), one acquire fence ----------
__device__ __forceinline__ void gate(const int* flag) {
    if (threadIdx.x == 0) {
        while (__hip_atomic_load(flag, __ATOMIC_RELAXED, __HIP_MEMORY_SCOPE_AGENT) == 0)
            __builtin_amdgcn_s_sleep(32);
    }
    __syncthreads();
    __builtin_amdgcn_fence(__ATOMIC_ACQUIRE, "agent");
}

// ---------- done: drain writes, bump counter; LAST producer sets the flag ----------
__device__ __forceinline__ void done(int* cnt, int target, int* flag) {
    __syncthreads();
    if (threadIdx.x == 0) {
        asm volatile("s_waitcnt vmcnt(0)" ::: "memory");
        int old = __hip_atomic_fetch_add(cnt, 1, __ATOMIC_RELAXED, __HIP_MEMORY_SCOPE_AGENT);
        if (old == target - 1)
            __hip_atomic_store(flag, 1, __ATOMIC_RELAXED, __HIP_MEMORY_SCOPE_AGENT);
    }
}

// ================= shared GEMM phase (R6/R9/R10-validated) =================
__device__ __forceinline__ void gemm_phase(
    const void* __restrict__ A, int af, int aact,
    const void* __restrict__ B, int bfB,
    float* __restrict__ C,
    int N, int K, int Kc, int k0, int n0,
    unsigned short (*Bs)[72], int tid)
{
    const int l  = tid & 63;
    const int lr = l & 15;
    const int lc = l >> 4;
    const int m0 = (tid >> 6) * 16;
    const int srow = tid >> 4;
    const int scol = (tid & 15) * 4;

    f32x4 acc0 = {0.f,0.f,0.f,0.f}, acc1 = {0.f,0.f,0.f,0.f};

    for (int kt = 0; kt < Kc; kt += 64) {
        if (!bfB) {
            float4 v = *(const float4*)((const float*)B + (size_t)(n0 + srow) * K + k0 + kt + scol);
            __syncthreads();
            Bs[srow][scol + 0] = f2b(v.x);
            Bs[srow][scol + 1] = f2b(v.y);
            Bs[srow][scol + 2] = f2b(v.z);
            Bs[srow][scol + 3] = f2b(v.w);
        } else {
            u16x4 v = *(const u16x4*)((const unsigned short*)B + (size_t)(n0 + srow) * K + k0 + kt + scol);
            __syncthreads();
            Bs[srow][scol + 0] = v.x;
            Bs[srow][scol + 1] = v.y;
            Bs[srow][scol + 2] = v.z;
            Bs[srow][scol + 3] = v.w;
        }
        __syncthreads();

        #pragma unroll
        for (int kc = 0; kc < 2; ++kc) {
            size_t aoff = (size_t)(m0 + lr) * K + k0 + kt + kc * 32 + lc * 8;
            bf16x8 a;
            if (!af) {
                a = *(const bf16x8*)((const unsigned short*)A + aoff);
            } else {
                const float* p = (const float*)A + aoff;
                float4 u0 = *(const float4*)p;
                float4 u1 = *(const float4*)(p + 4);
                if (aact) {
                    u0.x = leaky(u0.x); u0.y = leaky(u0.y);
                    u0.z = leaky(u0.z); u0.w = leaky(u0.w);
                    u1.x = leaky(u1.x); u1.y = leaky(u1.y);
                    u1.z = leaky(u1.z); u1.w = leaky(u1.w);
                }
                a = cvt8(u0, u1);
            }
            bf16x8 b0 = *(const bf16x8*)&Bs[lr][kc * 32 + lc * 8];
            bf16x8 b1 = *(const bf16x8*)&Bs[16 + lr][kc * 32 + lc * 8];
            acc0 = __builtin_amdgcn_mfma_f32_16x16x32_bf16(a, b0, acc0, 0, 0, 0);
            acc1 = __builtin_amdgcn_mfma_f32_16x16x32_bf16(a, b1, acc1, 0, 0, 0);
        }
    }

    #pragma unroll
    for (int r = 0; r < 4; ++r) {
        int m = m0 + lc * 4 + r;
        atomicAdd(&C[(size_t)m * N + n0 + lr],      acc0[r]);
        atomicAdd(&C[(size_t)m * N + n0 + 16 + lr], acc1[r]);
    }
}

// ================= D2: fused L1 + L2 + tail + finalize (768 blocks, flag gates) =================
// bid [0,256):   C2o += xd_b @ ow1^T   (N=1024,K=2048,S=8)
// bid [256,384): C2s += xm_b @ Ws1^T   (N=1024,K=512, S=4)
// bid [384,640): gated: C3{o,s} += leaky(C2{o,s}) @ {ow2,sw2}^T  (N=512,K=1024,S=8)
// bid [640,768): gated: per-sample tail; last-arriving block finalizes.
__global__ __launch_bounds__(512, 4) void fused_kernel(
    float* __restrict__ wf,
    const unsigned short* __restrict__ xm_b, const unsigned short* __restrict__ xd_b,
    const unsigned short* __restrict__ Ws1,
    const float* __restrict__ ow1, const float* __restrict__ ow2, const float* __restrict__ ow3,
    const float* __restrict__ sw2, const float* __restrict__ sw3,
    const float* __restrict__ tw1, const float* __restrict__ tw2,
    const float* __restrict__ cw1, const float* __restrict__ cw2,
    const float* __restrict__ qw1, const float* __restrict__ qw2,
    const float* __restrict__ center, const float* __restrict__ proto,
    float* __restrict__ out)
{
    __shared__ unsigned short Bs[32][72];
    __shared__ float o2r[512], s2r[512];
    __shared__ float red[2][64][4];
    __shared__ float o3s[64], s3s[64], t1s[64], c1s[64], q1s[64];
    __shared__ float tmp[4][8];
    __shared__ int flag_sh;

    float* C2o = wf;                    // [128,1024]
    float* C2s = wf + 131072;           // [128,1024]
    float* C3o = wf + 262144;           // [128,512]
    float* C3s = wf + 327680;           // [128,512]
    int*   cntL1  = (int*)(wf + 393216);        // 128B-spaced lines, zeroed by D1
    int*   flagL1 = (int*)(wf + 393216 + 32);
    int*   cntL2  = (int*)(wf + 393216 + 64);
    int*   flagL2 = (int*)(wf + 393216 + 96);
    int*   cntT   = (int*)(wf + 393216 + 128);
    float* ce_t = wf + 393472;          // [128] x4
    float* osv  = ce_t + 128;
    float* csv  = ce_t + 256;
    float* alv  = ce_t + 384;

    const int bid = blockIdx.x;
    const int tid = threadIdx.x;

    if (bid < 256) {
        int nt = bid >> 3, s = bid & 7;
        gemm_phase(xd_b, 0, 0, ow1, 0, C2o, 1024, 2048, 256, s * 256, nt * 32, Bs, tid);
        done(cntL1, 384, flagL1);
        return;
    }
    if (bid < 384) {
        int idx = bid - 256, nt = idx >> 2, s = idx & 3;
        gemm_phase(xm_b, 0, 0, Ws1, 1, C2s, 1024, 512, 128, s * 128, nt * 32, Bs, tid);
        done(cntL1, 384, flagL1);
        return;
    }
    if (bid < 640) {
        gate(flagL1);
        int b3 = bid - 384;
        int z = b3 >> 7, idx = b3 & 127, nt = idx >> 3, s = idx & 7;
        gemm_phase(z ? (const void*)C2s : (const void*)C2o, 1, 1,
                   z ? (const void*)sw2 : (const void*)ow2, 0,
                   z ? C3s : C3o, 512, 1024, 128, s * 128, nt * 32, Bs, tid);
        done(cntL2, 256, flagL2);
        return;
    }

    // ---------------- tail ----------------
    const int b = bid - 640;
    gate(flagL2);

    {   // layer-2 activation (512 threads, 1 elem each path)
        int e = tid;
        o2r[e] = leaky(C3o[b * 512 + e]);
        s2r[e] = leaky(C3s[b * 512 + e]);
    }
    __syncthreads();
    {   // both layer-3 matvecs: p=path, o=output, q=K-quarter
        int p = tid >> 8, o = (tid >> 2) & 63, q = tid & 3;
        const float* wr = (p ? sw3 : ow3) + (size_t)o * 512 + q * 128;
        const float* xr = (p ? s2r : o2r) + q * 128;
        float acc = 0.f;
        for (int j = 0; j < 128; ++j) acc += wr[j] * xr[j];
        red[p][o][q] = acc;
    }
    __syncthreads();
    if (tid < 128) {
        int p = tid >> 6, o = tid & 63;
        float v = leaky(red[p][o][0] + red[p][o][1] + red[p][o][2] + red[p][o][3]);
        if (p) s3s[o] = v; else o3s[o] = v;
    }
    __syncthreads();

    float ce_val = 0.f;
    int o = tid;
    if (tid < 64) {
        float acc = 0.f;
        for (int j = 0; j < 64; ++j) acc += tw1[o * 128 + j] * s3s[j];
        for (int j = 0; j < 64; ++j) acc += tw1[o * 128 + 64 + j] * (s3s[j] - center[j]);
        t1s[o] = leaky(acc);
    }
    __syncthreads();
    if (tid < 64) {
        float acc = 0.f;
        for (int j = 0; j < 64; ++j) acc += tw2[o * 64 + j] * t1s[j];
        float tex = leaky(acc);
        float sim[4];
        #pragma unroll
        for (int k = 0; k < 4; ++k) {
            float d = tex - proto[k * 64 + o];
            float v = d * d;
            #pragma unroll
            for (int off = 32; off; off >>= 1) v += __shfl_xor(v, off);
            sim[k] = v;
        }
        int cat = 0; float best = sim[0];
        #pragma unroll
        for (int k = 1; k < 4; ++k) if (sim[k] > best) { best = sim[k]; cat = k; }
        float sume = 0.f;
        #pragma unroll
        for (int k = 0; k < 4; ++k) sume += expf(sim[k] - best);
        ce_val = logf(sume);
        float acc2 = 0.f;
        for (int j = 0; j < 64; ++j) acc2 += cw1[o * 128 + j] * o3s[j];
        for (int j = 0; j < 64; ++j) acc2 += cw1[o * 128 + 64 + j] * (o3s[j] - proto[cat * 64 + j]);
        c1s[o] = leaky(acc2);
        acc2 = 0.f;
        for (int j = 0; j < 64; ++j) acc2 += qw1[o * 64 + j] * o3s[j];
        q1s[o] = leaky(acc2);
    }
    __syncthreads();
    if (tid < 64) {
        float acc = 0.f;
        for (int j = 0; j < 64; ++j) acc += cw2[o * 64 + j] * c1s[j];
        float cf = leaky(acc);
        float dc = cf - center[o];
        float cs = dc * dc;
        #pragma unroll
        for (int off = 32; off; off >>= 1) cs += __shfl_xor(cs, off);
        acc = 0.f;
        for (int j = 0; j < 64; ++j) acc += qw2[o * 64 + j] * q1s[j];
        float qf = leaky(acc);
        float dq = qf - center[o];
        float os = dq * dq;
        #pragma unroll
        for (int off = 32; off; off >>= 1) os += __shfl_xor(os, off);
        if (o == 0) {
            __hip_atomic_store(&ce_t[b], ce_val, __ATOMIC_RELAXED, __HIP_MEMORY_SCOPE_AGENT);
            __hip_atomic_store(&osv[b],  os,     __ATOMIC_RELAXED, __HIP_MEMORY_SCOPE_AGENT);
            __hip_atomic_store(&csv[b],  cs,     __ATOMIC_RELAXED, __HIP_MEMORY_SCOPE_AGENT);
            __hip_atomic_store(&alv[b],  fabsf(os - cs), __ATOMIC_RELAXED, __HIP_MEMORY_SCOPE_AGENT);
        }
    }
    __syncthreads();
    if (tid == 0) {
        asm volatile("s_waitcnt vmcnt(0)" ::: "memory");
        int old = __hip_atomic_fetch_add(cntT, 1, __ATOMIC_ACQ_REL, __HIP_MEMORY_SCOPE_AGENT);
        flag_sh = (old == 127);
    }
    __syncthreads();
    if (flag_sh) {
        float v0 = 0.f, v1 = 0.f, v2 = 0.f, v3 = 0.f;
        if (tid < 128) {
            v0 = __hip_atomic_load(&ce_t[tid], __ATOMIC_RELAXED, __HIP_MEMORY_SCOPE_AGENT);
            v1 = __hip_atomic_load(&osv[tid],  __ATOMIC_RELAXED, __HIP_MEMORY_SCOPE_AGENT);
            v2 = __hip_atomic_load(&csv[tid],  __ATOMIC_RELAXED, __HIP_MEMORY_SCOPE_AGENT);
            v3 = __hip_atomic_load(&alv[tid],  __ATOMIC_RELAXED, __HIP_MEMORY_SCOPE_AGENT);
        }
        float v[4] = { v0, v1, v2, v3 };
        int lane = tid & 63, wv = tid >> 6;
        #pragma unroll
        for (int i = 0; i < 4; ++i) {
            float x = v[i];
            #pragma unroll
            for (int off = 32; off; off >>= 1) x += __shfl_xor(x, off);
            if (lane == 0) tmp[i][wv] = x;
        }
        __syncthreads();
        if (tid < 4) {
            float s = 0.f;
            #pragma unroll
            for (int j = 0; j < 8; ++j) s += tmp[tid][j];
            out[tid] = s * (1.0f / 128.0f);
        }
    }
}

// ================= launcher =================
extern "C" void kernel_launch(void* const* d_in, const int* in_sizes, int n_in,
                              void* d_out, int out_size, void* d_ws, size_t ws_size,
                              hipStream_t stream)
{
    const float* x_mid     = (const float*)d_in[0];
    const float* x_deep    = (const float*)d_in[1];
    const float* w_shallow = (const float*)d_in[2];
    const float* ow1 = (const float*)d_in[3];
    const float* ow2 = (const float*)d_in[4];
    const float* ow3 = (const float*)d_in[5];
    const float* sw1 = (const float*)d_in[6];
    const float* sw2 = (const float*)d_in[7];
    const float* sw3 = (const float*)d_in[8];
    const float* tw1 = (const float*)d_in[9];
    const float* tw2 = (const float*)d_in[10];
    const float* cw1 = (const float*)d_in[11];
    const float* cw2 = (const float*)d_in[12];
    const float* qw1 = (const float*)d_in[13];
    const float* qw2 = (const float*)d_in[14];
    const float* center = (const float*)d_in[15];
    const float* proto  = (const float*)d_in[16];
    float* out = (float*)d_out;

    float* wf = (float*)d_ws;
    // zero region: wf[0 .. 394240)  (C2o,C2s,C3o,C3s, counters/flags, ce_t..alv)
    unsigned short* Ws1  = (unsigned short*)(wf + 394240);      // [1024,512] bf16
    unsigned short* xm_b = Ws1 + 524288;                        // [128,512]
    unsigned short* xd_b = xm_b + 65536;                        // [128,2048]

    // D1: Wfuse(64, LDS-staged) + mid means(16384) + deep means(16384) + zero(385)
    prep_kernel<<<33217, 256, 0, stream>>>(x_mid, x_deep, sw1, w_shallow,
                                           Ws1, xm_b, xd_b, (float4*)wf);

    // D2: fused L1+L2+tail+finalize (768 blocks, flag-gated)
    fused_kernel<<<768, 512, 0, stream>>>(wf, xm_b, xd_b, Ws1,
                                          ow1, ow2, ow3, sw2, sw3,
                                          tw1, tw2, cw1, cw2, qw1, qw2,
                                          center, proto, out);
}

// Round 12
// 134.442 us; speedup vs baseline: 1.4289x; 1.4289x over previous
//
#include <hip/hip_runtime.h>
#include <hip/hip_bf16.h>
#include <math.h>

typedef __attribute__((ext_vector_type(8))) short bf16x8;
typedef __attribute__((ext_vector_type(4))) float f32x4;

__device__ __forceinline__ float leaky(float x) { return x > 0.0f ? x : 0.01f * x; }

__device__ __forceinline__ unsigned short f2b(float f) {
    unsigned u = __builtin_bit_cast(unsigned, f);
    u += 0x7fffu + ((u >> 16) & 1u);
    return (unsigned short)(u >> 16);
}

__device__ __forceinline__ bf16x8 cvt8(float4 u0, float4 u1) {
    bf16x8 r;
    r[0] = (short)f2b(u0.x); r[1] = (short)f2b(u0.y);
    r[2] = (short)f2b(u0.z); r[3] = (short)f2b(u0.w);
    r[4] = (short)f2b(u1.x); r[5] = (short)f2b(u1.y);
    r[6] = (short)f2b(u1.z); r[7] = (short)f2b(u1.w);
    return r;
}

// ================= D1: both HW means -> bf16 ; zero atomic-C region =================
// blk [0,16384):     x_mid  [128,512,28,28] -> xm_b
// blk [16384,32768): x_deep [128,2048,7,7]  -> xd_b
// blk [32768,33409): zero wf[0..656384)  (C1,C2o,C2s,C3o,C3s,counters,scalars)
__global__ __launch_bounds__(256) void means_kernel(const float* __restrict__ xm,
                                                    const float* __restrict__ xd,
                                                    unsigned short* __restrict__ xm_b,
                                                    unsigned short* __restrict__ xd_b,
                                                    float4* __restrict__ zbase)
{
    int blk = blockIdx.x;
    int tid = threadIdx.x;
    if (blk >= 32768) {
        int idx = (blk - 32768) * 256 + tid;       // 641 blocks * 256 float4 = 656384 floats
        zbase[idx] = make_float4(0.f, 0.f, 0.f, 0.f);
        return;
    }
    if (blk < 16384) {
        int lane = tid & 63;
        int wid  = tid >> 6;
        int row  = blk * 4 + wid;                  // 0..65535
        const float4* r = (const float4*)(xm + (size_t)row * 784);
        float s = 0.0f;
        for (int i = lane; i < 196; i += 64) {
            float4 v = r[i];
            s += v.x + v.y + v.z + v.w;
        }
        #pragma unroll
        for (int off = 32; off; off >>= 1) s += __shfl_xor(s, off);
        if (lane == 0) xm_b[row] = f2b(s * (1.0f / 784.0f));
    } else {
        int b2  = blk - 16384;
        int sub = tid & 15;
        int r   = tid >> 4;
        int row = b2 * 16 + r;                     // 0..262143
        const float* base = xd + (size_t)row * 49;
        float s = base[sub] + base[sub + 16] + base[sub + 32];
        if (sub == 0) s += base[48];
        #pragma unroll
        for (int off = 8; off; off >>= 1) s += __shfl_xor(s, off);
        if (sub == 0) xd_b[row] = f2b(s * (1.0f / 49.0f));
    }
}

// ---------- gate: poll write-once FLAG (relaxed LLC load + backoff), one acquire fence ----------
__device__ __forceinline__ void gate(const int* flag) {
    if (threadIdx.x == 0) {
        while (__hip_atomic_load(flag, __ATOMIC_RELAXED, __HIP_MEMORY_SCOPE_AGENT) == 0)
            __builtin_amdgcn_s_sleep(32);
    }
    __syncthreads();
    __builtin_amdgcn_fence(__ATOMIC_ACQUIRE, "agent");
}

// ---------- done: drain writes, bump counter; LAST producer sets the flag ----------
__device__ __forceinline__ void done(int* cnt, int target, int* flag) {
    __syncthreads();
    if (threadIdx.x == 0) {
        asm volatile("s_waitcnt vmcnt(0)" ::: "memory");
        int old = __hip_atomic_fetch_add(cnt, 1, __ATOMIC_RELAXED, __HIP_MEMORY_SCOPE_AGENT);
        if (old == target - 1)
            __hip_atomic_store(flag, 1, __ATOMIC_RELAXED, __HIP_MEMORY_SCOPE_AGENT);
    }
}

// ================= shared GEMM phase (R6/R10-validated) =================
// C[m][n] += actA(A[m][k-slice]) @ B[n][k-slice]^T, atomic fp32 C; fp32 B staged to LDS as bf16.
// block 512 thr = 8 waves; wave w rows 16w..16w+15, cols n0..n0+31.
// A lane layout: row=l&15, kchunk=(l>>4)*8 ; C/D: col=l&15, row=(l>>4)*4+reg
__device__ __forceinline__ void gemm_phase(
    const void* __restrict__ A, int af, int aact,
    const float* __restrict__ B,
    float* __restrict__ C,
    int N, int K, int Kc, int k0, int n0,
    unsigned short (*Bs)[72], int tid)
{
    const int l  = tid & 63;
    const int lr = l & 15;
    const int lc = l >> 4;
    const int m0 = (tid >> 6) * 16;
    const int srow = tid >> 4;                     // 0..31
    const int scol = (tid & 15) * 4;               // 0,4,..,60

    f32x4 acc0 = {0.f,0.f,0.f,0.f}, acc1 = {0.f,0.f,0.f,0.f};

    for (int kt = 0; kt < Kc; kt += 64) {
        float4 v = *(const float4*)(B + (size_t)(n0 + srow) * K + k0 + kt + scol);
        __syncthreads();                           // prev-iter Bs reads done
        Bs[srow][scol + 0] = f2b(v.x);
        Bs[srow][scol + 1] = f2b(v.y);
        Bs[srow][scol + 2] = f2b(v.z);
        Bs[srow][scol + 3] = f2b(v.w);
        __syncthreads();

        #pragma unroll
        for (int kc = 0; kc < 2; ++kc) {
            size_t aoff = (size_t)(m0 + lr) * K + k0 + kt + kc * 32 + lc * 8;
            bf16x8 a;
            if (!af) {
                a = *(const bf16x8*)((const unsigned short*)A + aoff);
            } else {
                const float* p = (const float*)A + aoff;
                float4 u0 = *(const float4*)p;
                float4 u1 = *(const float4*)(p + 4);
                if (aact) {
                    u0.x = leaky(u0.x); u0.y = leaky(u0.y);
                    u0.z = leaky(u0.z); u0.w = leaky(u0.w);
                    u1.x = leaky(u1.x); u1.y = leaky(u1.y);
                    u1.z = leaky(u1.z); u1.w = leaky(u1.w);
                }
                a = cvt8(u0, u1);
            }
            bf16x8 b0 = *(const bf16x8*)&Bs[lr][kc * 32 + lc * 8];
            bf16x8 b1 = *(const bf16x8*)&Bs[16 + lr][kc * 32 + lc * 8];
            acc0 = __builtin_amdgcn_mfma_f32_16x16x32_bf16(a, b0, acc0, 0, 0, 0);
            acc1 = __builtin_amdgcn_mfma_f32_16x16x32_bf16(a, b1, acc1, 0, 0, 0);
        }
    }

    #pragma unroll
    for (int r = 0; r < 4; ++r) {
        int m = m0 + lc * 4 + r;
        atomicAdd(&C[(size_t)m * N + n0 + lr],      acc0[r]);
        atomicAdd(&C[(size_t)m * N + n0 + 16 + lr], acc1[r]);
    }
}

// ================= D2: gated fused G1 -> G2 -> G3 -> tail (1152 blocks) =================
// bid [0,256):     G1  C1 += xm_b @ wsh^T            (N=2048,K=512, S=4)   -> cntA/flagA
// bid [256,512):   G2o C2o += xd_b @ ow1^T           (N=1024,K=2048,S=8)   -> cntB
// bid [512,768):   G2s gate(A): C2s += C1 @ sw1^T    (N=1024,K=2048,S=8)   -> cntB/flagB@512
// bid [768,1024):  G3  gate(B): C3{o,s} += leaky(C2{o,s}) @ {ow2,sw2}^T    -> cntC/flagC
// bid [1024,1152): tail gate(C): per-sample; last-arriving block finalizes.
__global__ __launch_bounds__(512, 4) void fused_kernel(
    float* __restrict__ wf,
    const unsigned short* __restrict__ xm_b, const unsigned short* __restrict__ xd_b,
    const float* __restrict__ wsh,
    const float* __restrict__ ow1, const float* __restrict__ ow2, const float* __restrict__ ow3,
    const float* __restrict__ sw1, const float* __restrict__ sw2, const float* __restrict__ sw3,
    const float* __restrict__ tw1, const float* __restrict__ tw2,
    const float* __restrict__ cw1, const float* __restrict__ cw2,
    const float* __restrict__ qw1, const float* __restrict__ qw2,
    const float* __restrict__ center, const float* __restrict__ proto,
    float* __restrict__ out)
{
    __shared__ unsigned short Bs[32][72];
    __shared__ float o2r[512], s2r[512];
    __shared__ float red[2][64][4];
    __shared__ float o3s[64], s3s[64], t1s[64], c1s[64], q1s[64];
    __shared__ float tmp[4][8];
    __shared__ int flag_sh;

    float* C1  = wf;                    // [128,2048]
    float* C2o = wf + 262144;           // [128,1024]
    float* C2s = wf + 393216;           // [128,1024]
    float* C3o = wf + 524288;           // [128,512]
    float* C3s = wf + 589824;           // [128,512]
    int*   cntA  = (int*)(wf + 655360);         // 128B-spaced lines, zeroed by D1
    int*   flagA = (int*)(wf + 655360 + 32);
    int*   cntB  = (int*)(wf + 655360 + 64);
    int*   flagB = (int*)(wf + 655360 + 96);
    int*   cntC  = (int*)(wf + 655360 + 128);
    int*   flagC = (int*)(wf + 655360 + 160);
    int*   cntT  = (int*)(wf + 655360 + 192);
    float* ce_t = wf + 655616;          // [128] x4
    float* osv  = ce_t + 128;
    float* csv  = ce_t + 256;
    float* alv  = ce_t + 384;

    const int bid = blockIdx.x;
    const int tid = threadIdx.x;

    if (bid < 256) {
        int nt = bid >> 2, s = bid & 3;
        gemm_phase(xm_b, 0, 0, wsh, C1, 2048, 512, 128, s * 128, nt * 32, Bs, tid);
        done(cntA, 256, flagA);
        return;
    }
    if (bid < 512) {
        int idx = bid - 256, nt = idx >> 3, s = idx & 7;
        gemm_phase(xd_b, 0, 0, ow1, C2o, 1024, 2048, 256, s * 256, nt * 32, Bs, tid);
        done(cntB, 512, flagB);
        return;
    }
    if (bid < 768) {
        gate(flagA);
        int idx = bid - 512, nt = idx >> 3, s = idx & 7;
        gemm_phase(C1, 1, 0, sw1, C2s, 1024, 2048, 256, s * 256, nt * 32, Bs, tid);
        done(cntB, 512, flagB);
        return;
    }
    if (bid < 1024) {
        gate(flagB);
        int b3 = bid - 768;
        int z = b3 >> 7, idx = b3 & 127, nt = idx >> 3, s = idx & 7;
        gemm_phase(z ? (const void*)C2s : (const void*)C2o, 1, 1,
                   z ? sw2 : ow2,
                   z ? C3s : C3o, 512, 1024, 128, s * 128, nt * 32, Bs, tid);
        done(cntC, 256, flagC);
        return;
    }

    // ---------------- tail ----------------
    const int b = bid - 1024;
    gate(flagC);

    {   // layer-2 activation (512 threads, 1 elem each path)
        int e = tid;
        o2r[e] = leaky(C3o[b * 512 + e]);
        s2r[e] = leaky(C3s[b * 512 + e]);
    }
    __syncthreads();
    {   // both layer-3 matvecs: p=path, o=output, q=K-quarter
        int p = tid >> 8, o = (tid >> 2) & 63, q = tid & 3;
        const float* wr = (p ? sw3 : ow3) + (size_t)o * 512 + q * 128;
        const float* xr = (p ? s2r : o2r) + q * 128;
        float acc = 0.f;
        for (int j = 0; j < 128; ++j) acc += wr[j] * xr[j];
        red[p][o][q] = acc;
    }
    __syncthreads();
    if (tid < 128) {
        int p = tid >> 6, o = tid & 63;
        float v = leaky(red[p][o][0] + red[p][o][1] + red[p][o][2] + red[p][o][3]);
        if (p) s3s[o] = v; else o3s[o] = v;
    }
    __syncthreads();

    float ce_val = 0.f;
    int o = tid;
    if (tid < 64) {
        float acc = 0.f;
        for (int j = 0; j < 64; ++j) acc += tw1[o * 128 + j] * s3s[j];
        for (int j = 0; j < 64; ++j) acc += tw1[o * 128 + 64 + j] * (s3s[j] - center[j]);
        t1s[o] = leaky(acc);
    }
    __syncthreads();
    if (tid < 64) {
        float acc = 0.f;
        for (int j = 0; j < 64; ++j) acc += tw2[o * 64 + j] * t1s[j];
        float tex = leaky(acc);
        float sim[4];
        #pragma unroll
        for (int k = 0; k < 4; ++k) {
            float d = tex - proto[k * 64 + o];
            float v = d * d;
            #pragma unroll
            for (int off = 32; off; off >>= 1) v += __shfl_xor(v, off);
            sim[k] = v;
        }
        int cat = 0; float best = sim[0];
        #pragma unroll
        for (int k = 1; k < 4; ++k) if (sim[k] > best) { best = sim[k]; cat = k; }
        float sume = 0.f;
        #pragma unroll
        for (int k = 0; k < 4; ++k) sume += expf(sim[k] - best);
        ce_val = logf(sume);
        float acc2 = 0.f;
        for (int j = 0; j < 64; ++j) acc2 += cw1[o * 128 + j] * o3s[j];
        for (int j = 0; j < 64; ++j) acc2 += cw1[o * 128 + 64 + j] * (o3s[j] - proto[cat * 64 + j]);
        c1s[o] = leaky(acc2);
        acc2 = 0.f;
        for (int j = 0; j < 64; ++j) acc2 += qw1[o * 64 + j] * o3s[j];
        q1s[o] = leaky(acc2);
    }
    __syncthreads();
    if (tid < 64) {
        float acc = 0.f;
        for (int j = 0; j < 64; ++j) acc += cw2[o * 64 + j] * c1s[j];
        float cf = leaky(acc);
        float dc = cf - center[o];
        float cs = dc * dc;
        #pragma unroll
        for (int off = 32; off; off >>= 1) cs += __shfl_xor(cs, off);
        acc = 0.f;
        for (int j = 0; j < 64; ++j) acc += qw2[o * 64 + j] * q1s[j];
        float qf = leaky(acc);
        float dq = qf - center[o];
        float os = dq * dq;
        #pragma unroll
        for (int off = 32; off; off >>= 1) os += __shfl_xor(os, off);
        if (o == 0) {
            __hip_atomic_store(&ce_t[b], ce_val, __ATOMIC_RELAXED, __HIP_MEMORY_SCOPE_AGENT);
            __hip_atomic_store(&osv[b],  os,     __ATOMIC_RELAXED, __HIP_MEMORY_SCOPE_AGENT);
            __hip_atomic_store(&csv[b],  cs,     __ATOMIC_RELAXED, __HIP_MEMORY_SCOPE_AGENT);
            __hip_atomic_store(&alv[b],  fabsf(os - cs), __ATOMIC_RELAXED, __HIP_MEMORY_SCOPE_AGENT);
        }
    }
    __syncthreads();
    if (tid == 0) {
        asm volatile("s_waitcnt vmcnt(0)" ::: "memory");
        int old = __hip_atomic_fetch_add(cntT, 1, __ATOMIC_ACQ_REL, __HIP_MEMORY_SCOPE_AGENT);
        flag_sh = (old == 127);
    }
    __syncthreads();
    if (flag_sh) {
        float v0 = 0.f, v1 = 0.f, v2 = 0.f, v3 = 0.f;
        if (tid < 128) {
            v0 = __hip_atomic_load(&ce_t[tid], __ATOMIC_RELAXED, __HIP_MEMORY_SCOPE_AGENT);
            v1 = __hip_atomic_load(&osv[tid],  __ATOMIC_RELAXED, __HIP_MEMORY_SCOPE_AGENT);
            v2 = __hip_atomic_load(&csv[tid],  __ATOMIC_RELAXED, __HIP_MEMORY_SCOPE_AGENT);
            v3 = __hip_atomic_load(&alv[tid],  __ATOMIC_RELAXED, __HIP_MEMORY_SCOPE_AGENT);
        }
        float v[4] = { v0, v1, v2, v3 };
        int lane = tid & 63, wv = tid >> 6;
        #pragma unroll
        for (int i = 0; i < 4; ++i) {
            float x = v[i];
            #pragma unroll
            for (int off = 32; off; off >>= 1) x += __shfl_xor(x, off);
            if (lane == 0) tmp[i][wv] = x;
        }
        __syncthreads();
        if (tid < 4) {
            float s = 0.f;
            #pragma unroll
            for (int j = 0; j < 8; ++j) s += tmp[tid][j];
            out[tid] = s * (1.0f / 128.0f);
        }
    }
}

// ================= launcher =================
extern "C" void kernel_launch(void* const* d_in, const int* in_sizes, int n_in,
                              void* d_out, int out_size, void* d_ws, size_t ws_size,
                              hipStream_t stream)
{
    const float* x_mid     = (const float*)d_in[0];
    const float* x_deep    = (const float*)d_in[1];
    const float* w_shallow = (const float*)d_in[2];
    const float* ow1 = (const float*)d_in[3];
    const float* ow2 = (const float*)d_in[4];
    const float* ow3 = (const float*)d_in[5];
    const float* sw1 = (const float*)d_in[6];
    const float* sw2 = (const float*)d_in[7];
    const float* sw3 = (const float*)d_in[8];
    const float* tw1 = (const float*)d_in[9];
    const float* tw2 = (const float*)d_in[10];
    const float* cw1 = (const float*)d_in[11];
    const float* cw2 = (const float*)d_in[12];
    const float* qw1 = (const float*)d_in[13];
    const float* qw2 = (const float*)d_in[14];
    const float* center = (const float*)d_in[15];
    const float* proto  = (const float*)d_in[16];
    float* out = (float*)d_out;

    float* wf = (float*)d_ws;
    // zero region: wf[0 .. 656384)  (C1,C2o,C2s,C3o,C3s, counters/flags, ce_t..alv)
    unsigned short* xm_b = (unsigned short*)(wf + 656384);            // [128,512]
    unsigned short* xd_b = xm_b + 65536;                              // [128,2048]

    // D1: means + zero (641 zero blocks)
    means_kernel<<<33409, 256, 0, stream>>>(x_mid, x_deep, xm_b, xd_b, (float4*)wf);

    // D2: gated fused G1+G2+G3+tail+finalize (1152 blocks, 4 blk/CU)
    fused_kernel<<<1152, 512, 0, stream>>>(wf, xm_b, xd_b, w_shallow,
                                           ow1, ow2, ow3, sw1, sw2, sw3,
                                           tw1, tw2, cw1, cw2, qw1, qw2,
                                           center, proto, out);
}

// Round 13
// 132.406 us; speedup vs baseline: 1.4509x; 1.0154x over previous
//
#include <hip/hip_runtime.h>
#include <hip/hip_bf16.h>
#include <math.h>

typedef __attribute__((ext_vector_type(8))) short bf16x8;
typedef __attribute__((ext_vector_type(4))) float f32x4;

__device__ __forceinline__ float leaky(float x) { return x > 0.0f ? x : 0.01f * x; }

__device__ __forceinline__ unsigned short f2b(float f) {
    unsigned u = __builtin_bit_cast(unsigned, f);
    u += 0x7fffu + ((u >> 16) & 1u);
    return (unsigned short)(u >> 16);
}

__device__ __forceinline__ bf16x8 cvt8(float4 u0, float4 u1) {
    bf16x8 r;
    r[0] = (short)f2b(u0.x); r[1] = (short)f2b(u0.y);
    r[2] = (short)f2b(u0.z); r[3] = (short)f2b(u0.w);
    r[4] = (short)f2b(u1.x); r[5] = (short)f2b(u1.y);
    r[6] = (short)f2b(u1.z); r[7] = (short)f2b(u1.w);
    return r;
}

// ================= D1: both HW means -> bf16 ; zero atomic-C region =================
__global__ __launch_bounds__(256) void means_kernel(const float* __restrict__ xm,
                                                    const float* __restrict__ xd,
                                                    unsigned short* __restrict__ xm_b,
                                                    unsigned short* __restrict__ xd_b,
                                                    float4* __restrict__ zbase)
{
    int blk = blockIdx.x;
    int tid = threadIdx.x;
    if (blk >= 32768) {
        int idx = (blk - 32768) * 256 + tid;       // 641 blocks * 256 float4 = 656384 floats
        zbase[idx] = make_float4(0.f, 0.f, 0.f, 0.f);
        return;
    }
    if (blk < 16384) {
        int lane = tid & 63;
        int wid  = tid >> 6;
        int row  = blk * 4 + wid;                  // 0..65535
        const float4* r = (const float4*)(xm + (size_t)row * 784);
        float s = 0.0f;
        for (int i = lane; i < 196; i += 64) {
            float4 v = r[i];
            s += v.x + v.y + v.z + v.w;
        }
        #pragma unroll
        for (int off = 32; off; off >>= 1) s += __shfl_xor(s, off);
        if (lane == 0) xm_b[row] = f2b(s * (1.0f / 784.0f));
    } else {
        int b2  = blk - 16384;
        int sub = tid & 15;
        int r   = tid >> 4;
        int row = b2 * 16 + r;                     // 0..262143
        const float* base = xd + (size_t)row * 49;
        float s = base[sub] + base[sub + 16] + base[sub + 32];
        if (sub == 0) s += base[48];
        #pragma unroll
        for (int off = 8; off; off >>= 1) s += __shfl_xor(s, off);
        if (sub == 0) xd_b[row] = f2b(s * (1.0f / 49.0f));
    }
}

// ---------- gate: poll write-once FLAG (relaxed LLC load + backoff), one acquire fence ----------
__device__ __forceinline__ void gate(const int* flag) {
    if (threadIdx.x == 0) {
        while (__hip_atomic_load(flag, __ATOMIC_RELAXED, __HIP_MEMORY_SCOPE_AGENT) == 0)
            __builtin_amdgcn_s_sleep(32);
    }
    __syncthreads();
    __builtin_amdgcn_fence(__ATOMIC_ACQUIRE, "agent");
}

// ---------- done: drain writes, bump counter; LAST producer sets the flag ----------
__device__ __forceinline__ void done(int* cnt, int target, int* flag) {
    __syncthreads();
    if (threadIdx.x == 0) {
        asm volatile("s_waitcnt vmcnt(0)" ::: "memory");
        int old = __hip_atomic_fetch_add(cnt, 1, __ATOMIC_RELAXED, __HIP_MEMORY_SCOPE_AGENT);
        if (old == target - 1)
            __hip_atomic_store(flag, 1, __ATOMIC_RELAXED, __HIP_MEMORY_SCOPE_AGENT);
    }
}

// ================= shared GEMM phase (R6/R10/R12-validated) =================
// C[m][n] += actA(A[m][k-slice]) @ B[n][k-slice]^T, atomic fp32 C; fp32 B staged to LDS as bf16.
// block 512 thr = 8 waves; wave w rows 16w..16w+15, cols n0..n0+31.
// A lane layout: row=l&15, kchunk=(l>>4)*8 ; C/D: col=l&15, row=(l>>4)*4+reg
__device__ __forceinline__ void gemm_phase(
    const void* __restrict__ A, int af, int aact,
    const float* __restrict__ B,
    float* __restrict__ C,
    int N, int K, int Kc, int k0, int n0,
    unsigned short (*Bs)[72], int tid)
{
    const int l  = tid & 63;
    const int lr = l & 15;
    const int lc = l >> 4;
    const int m0 = (tid >> 6) * 16;
    const int srow = tid >> 4;                     // 0..31
    const int scol = (tid & 15) * 4;               // 0,4,..,60

    f32x4 acc0 = {0.f,0.f,0.f,0.f}, acc1 = {0.f,0.f,0.f,0.f};

    for (int kt = 0; kt < Kc; kt += 64) {
        float4 v = *(const float4*)(B + (size_t)(n0 + srow) * K + k0 + kt + scol);
        __syncthreads();                           // prev-iter Bs reads done
        Bs[srow][scol + 0] = f2b(v.x);
        Bs[srow][scol + 1] = f2b(v.y);
        Bs[srow][scol + 2] = f2b(v.z);
        Bs[srow][scol + 3] = f2b(v.w);
        __syncthreads();

        #pragma unroll
        for (int kc = 0; kc < 2; ++kc) {
            size_t aoff = (size_t)(m0 + lr) * K + k0 + kt + kc * 32 + lc * 8;
            bf16x8 a;
            if (!af) {
                a = *(const bf16x8*)((const unsigned short*)A + aoff);
            } else {
                const float* p = (const float*)A + aoff;
                float4 u0 = *(const float4*)p;
                float4 u1 = *(const float4*)(p + 4);
                if (aact) {
                    u0.x = leaky(u0.x); u0.y = leaky(u0.y);
                    u0.z = leaky(u0.z); u0.w = leaky(u0.w);
                    u1.x = leaky(u1.x); u1.y = leaky(u1.y);
                    u1.z = leaky(u1.z); u1.w = leaky(u1.w);
                }
                a = cvt8(u0, u1);
            }
            bf16x8 b0 = *(const bf16x8*)&Bs[lr][kc * 32 + lc * 8];
            bf16x8 b1 = *(const bf16x8*)&Bs[16 + lr][kc * 32 + lc * 8];
            acc0 = __builtin_amdgcn_mfma_f32_16x16x32_bf16(a, b0, acc0, 0, 0, 0);
            acc1 = __builtin_amdgcn_mfma_f32_16x16x32_bf16(a, b1, acc1, 0, 0, 0);
        }
    }

    #pragma unroll
    for (int r = 0; r < 4; ++r) {
        int m = m0 + lc * 4 + r;
        atomicAdd(&C[(size_t)m * N + n0 + lr],      acc0[r]);
        atomicAdd(&C[(size_t)m * N + n0 + 16 + lr], acc1[r]);
    }
}

// ================= D2: fused, R10 topology (896 blocks, only 2 pure-spin levels) ======
// bid [0,256):   G1: C1 += xm_b @ wsh^T (S=4) ; self-barrier flagA ; then
//                G2s: C2s += C1 @ sw1^T (S=8)                       -> cntB
// bid [256,512): G2o: C2o += xd_b @ ow1^T (S=8)                     -> cntB/flagB@512
// bid [512,768): gate(B): G3 C3{o,s} += leaky(C2{o,s}) @ {ow2,sw2}^T -> cntC/flagC
// bid [768,896): gate(C): per-sample tail; last-arriving block finalizes.
__global__ __launch_bounds__(512, 4) void fused_kernel(
    float* __restrict__ wf,
    const unsigned short* __restrict__ xm_b, const unsigned short* __restrict__ xd_b,
    const float* __restrict__ wsh,
    const float* __restrict__ ow1, const float* __restrict__ ow2, const float* __restrict__ ow3,
    const float* __restrict__ sw1, const float* __restrict__ sw2, const float* __restrict__ sw3,
    const float* __restrict__ tw1, const float* __restrict__ tw2,
    const float* __restrict__ cw1, const float* __restrict__ cw2,
    const float* __restrict__ qw1, const float* __restrict__ qw2,
    const float* __restrict__ center, const float* __restrict__ proto,
    float* __restrict__ out)
{
    __shared__ unsigned short Bs[32][72];
    __shared__ float o2r[512], s2r[512];
    __shared__ float red[2][64][4];
    __shared__ float o3s[64], s3s[64], t1s[64], c1s[64], q1s[64];
    __shared__ float tmp[4][8];
    __shared__ int flag_sh;

    float* C1  = wf;                    // [128,2048]
    float* C2o = wf + 262144;           // [128,1024]
    float* C2s = wf + 393216;           // [128,1024]
    float* C3o = wf + 524288;           // [128,512]
    float* C3s = wf + 589824;           // [128,512]
    int*   cntA  = (int*)(wf + 655360);         // 128B-spaced lines, zeroed by D1
    int*   flagA = (int*)(wf + 655360 + 32);
    int*   cntB  = (int*)(wf + 655360 + 64);
    int*   flagB = (int*)(wf + 655360 + 96);
    int*   cntC  = (int*)(wf + 655360 + 128);
    int*   flagC = (int*)(wf + 655360 + 160);
    int*   cntT  = (int*)(wf + 655360 + 192);
    float* ce_t = wf + 655616;          // [128] x4
    float* osv  = ce_t + 128;
    float* csv  = ce_t + 256;
    float* alv  = ce_t + 384;

    const int bid = blockIdx.x;
    const int tid = threadIdx.x;

    if (bid < 256) {
        // G1: N=2048, K=512, S=4 -> 64 n-tiles x 4 slices
        {
            int nt = bid >> 2, s = bid & 3;
            gemm_phase(xm_b, 0, 0, wsh, C1, 2048, 512, 128, s * 128, nt * 32, Bs, tid);
        }
        done(cntA, 256, flagA);
        gate(flagA);                               // self-barrier: all 256 resident workers
        // G2s: N=1024, K=2048, S=8 -> 32 n-tiles x 8 slices
        {
            int nt = bid >> 3, s = bid & 7;
            gemm_phase(C1, 1, 0, sw1, C2s, 1024, 2048, 256, s * 256, nt * 32, Bs, tid);
        }
        done(cntB, 512, flagB);
        return;
    }
    if (bid < 512) {
        int idx = bid - 256, nt = idx >> 3, s = idx & 7;
        gemm_phase(xd_b, 0, 0, ow1, C2o, 1024, 2048, 256, s * 256, nt * 32, Bs, tid);
        done(cntB, 512, flagB);
        return;
    }
    if (bid < 768) {
        gate(flagB);
        int b3 = bid - 512;
        int z = b3 >> 7, idx = b3 & 127, nt = idx >> 3, s = idx & 7;
        gemm_phase(z ? (const void*)C2s : (const void*)C2o, 1, 1,
                   z ? sw2 : ow2,
                   z ? C3s : C3o, 512, 1024, 128, s * 128, nt * 32, Bs, tid);
        done(cntC, 256, flagC);
        return;
    }

    // ---------------- tail ----------------
    const int b = bid - 768;
    gate(flagC);

    {   // layer-2 activation (512 threads, 1 elem each path)
        int e = tid;
        o2r[e] = leaky(C3o[b * 512 + e]);
        s2r[e] = leaky(C3s[b * 512 + e]);
    }
    __syncthreads();
    {   // both layer-3 matvecs: p=path, o=output, q=K-quarter
        int p = tid >> 8, o = (tid >> 2) & 63, q = tid & 3;
        const float* wr = (p ? sw3 : ow3) + (size_t)o * 512 + q * 128;
        const float* xr = (p ? s2r : o2r) + q * 128;
        float acc = 0.f;
        for (int j = 0; j < 128; ++j) acc += wr[j] * xr[j];
        red[p][o][q] = acc;
    }
    __syncthreads();
    if (tid < 128) {
        int p = tid >> 6, o = tid & 63;
        float v = leaky(red[p][o][0] + red[p][o][1] + red[p][o][2] + red[p][o][3]);
        if (p) s3s[o] = v; else o3s[o] = v;
    }
    __syncthreads();

    float ce_val = 0.f;
    int o = tid;
    if (tid < 64) {
        float acc = 0.f;
        for (int j = 0; j < 64; ++j) acc += tw1[o * 128 + j] * s3s[j];
        for (int j = 0; j < 64; ++j) acc += tw1[o * 128 + 64 + j] * (s3s[j] - center[j]);
        t1s[o] = leaky(acc);
    }
    __syncthreads();
    if (tid < 64) {
        float acc = 0.f;
        for (int j = 0; j < 64; ++j) acc += tw2[o * 64 + j] * t1s[j];
        float tex = leaky(acc);
        float sim[4];
        #pragma unroll
        for (int k = 0; k < 4; ++k) {
            float d = tex - proto[k * 64 + o];
            float v = d * d;
            #pragma unroll
            for (int off = 32; off; off >>= 1) v += __shfl_xor(v, off);
            sim[k] = v;
        }
        int cat = 0; float best = sim[0];
        #pragma unroll
        for (int k = 1; k < 4; ++k) if (sim[k] > best) { best = sim[k]; cat = k; }
        float sume = 0.f;
        #pragma unroll
        for (int k = 0; k < 4; ++k) sume += expf(sim[k] - best);
        ce_val = logf(sume);
        float acc2 = 0.f;
        for (int j = 0; j < 64; ++j) acc2 += cw1[o * 128 + j] * o3s[j];
        for (int j = 0; j < 64; ++j) acc2 += cw1[o * 128 + 64 + j] * (o3s[j] - proto[cat * 64 + j]);
        c1s[o] = leaky(acc2);
        acc2 = 0.f;
        for (int j = 0; j < 64; ++j) acc2 += qw1[o * 64 + j] * o3s[j];
        q1s[o] = leaky(acc2);
    }
    __syncthreads();
    if (tid < 64) {
        float acc = 0.f;
        for (int j = 0; j < 64; ++j) acc += cw2[o * 64 + j] * c1s[j];
        float cf = leaky(acc);
        float dc = cf - center[o];
        float cs = dc * dc;
        #pragma unroll
        for (int off = 32; off; off >>= 1) cs += __shfl_xor(cs, off);
        acc = 0.f;
        for (int j = 0; j < 64; ++j) acc += qw2[o * 64 + j] * q1s[j];
        float qf = leaky(acc);
        float dq = qf - center[o];
        float os = dq * dq;
        #pragma unroll
        for (int off = 32; off; off >>= 1) os += __shfl_xor(os, off);
        if (o == 0) {
            __hip_atomic_store(&ce_t[b], ce_val, __ATOMIC_RELAXED, __HIP_MEMORY_SCOPE_AGENT);
            __hip_atomic_store(&osv[b],  os,     __ATOMIC_RELAXED, __HIP_MEMORY_SCOPE_AGENT);
            __hip_atomic_store(&csv[b],  cs,     __ATOMIC_RELAXED, __HIP_MEMORY_SCOPE_AGENT);
            __hip_atomic_store(&alv[b],  fabsf(os - cs), __ATOMIC_RELAXED, __HIP_MEMORY_SCOPE_AGENT);
        }
    }
    __syncthreads();
    if (tid == 0) {
        asm volatile("s_waitcnt vmcnt(0)" ::: "memory");
        int old = __hip_atomic_fetch_add(cntT, 1, __ATOMIC_ACQ_REL, __HIP_MEMORY_SCOPE_AGENT);
        flag_sh = (old == 127);
    }
    __syncthreads();
    if (flag_sh) {
        float v0 = 0.f, v1 = 0.f, v2 = 0.f, v3 = 0.f;
        if (tid < 128) {
            v0 = __hip_atomic_load(&ce_t[tid], __ATOMIC_RELAXED, __HIP_MEMORY_SCOPE_AGENT);
            v1 = __hip_atomic_load(&osv[tid],  __ATOMIC_RELAXED, __HIP_MEMORY_SCOPE_AGENT);
            v2 = __hip_atomic_load(&csv[tid],  __ATOMIC_RELAXED, __HIP_MEMORY_SCOPE_AGENT);
            v3 = __hip_atomic_load(&alv[tid],  __ATOMIC_RELAXED, __HIP_MEMORY_SCOPE_AGENT);
        }
        float v[4] = { v0, v1, v2, v3 };
        int lane = tid & 63, wv = tid >> 6;
        #pragma unroll
        for (int i = 0; i < 4; ++i) {
            float x = v[i];
            #pragma unroll
            for (int off = 32; off; off >>= 1) x += __shfl_xor(x, off);
            if (lane == 0) tmp[i][wv] = x;
        }
        __syncthreads();
        if (tid < 4) {
            float s = 0.f;
            #pragma unroll
            for (int j = 0; j < 8; ++j) s += tmp[tid][j];
            out[tid] = s * (1.0f / 128.0f);
        }
    }
}

// ================= launcher =================
extern "C" void kernel_launch(void* const* d_in, const int* in_sizes, int n_in,
                              void* d_out, int out_size, void* d_ws, size_t ws_size,
                              hipStream_t stream)
{
    const float* x_mid     = (const float*)d_in[0];
    const float* x_deep    = (const float*)d_in[1];
    const float* w_shallow = (const float*)d_in[2];
    const float* ow1 = (const float*)d_in[3];
    const float* ow2 = (const float*)d_in[4];
    const float* ow3 = (const float*)d_in[5];
    const float* sw1 = (const float*)d_in[6];
    const float* sw2 = (const float*)d_in[7];
    const float* sw3 = (const float*)d_in[8];
    const float* tw1 = (const float*)d_in[9];
    const float* tw2 = (const float*)d_in[10];
    const float* cw1 = (const float*)d_in[11];
    const float* cw2 = (const float*)d_in[12];
    const float* qw1 = (const float*)d_in[13];
    const float* qw2 = (const float*)d_in[14];
    const float* center = (const float*)d_in[15];
    const float* proto  = (const float*)d_in[16];
    float* out = (float*)d_out;

    float* wf = (float*)d_ws;
    // zero region: wf[0 .. 656384)  (C1,C2o,C2s,C3o,C3s, counters/flags, ce_t..alv)
    unsigned short* xm_b = (unsigned short*)(wf + 656384);            // [128,512]
    unsigned short* xd_b = xm_b + 65536;                              // [128,2048]

    // D1: means + zero (641 zero blocks)
    means_kernel<<<33409, 256, 0, stream>>>(x_mid, x_deep, xm_b, xd_b, (float4*)wf);

    // D2: fused with R10-proven topology (896 blocks, 2 pure-spin levels)
    fused_kernel<<<896, 512, 0, stream>>>(wf, xm_b, xd_b, w_shallow,
                                          ow1, ow2, ow3, sw1, sw2, sw3,
                                          tw1, tw2, cw1, cw2, qw1, qw2,
                                          center, proto, out);
}

// Round 14
// 110.783 us; speedup vs baseline: 1.7340x; 1.1952x over previous
//
#include <hip/hip_runtime.h>
#include <hip/hip_bf16.h>
#include <math.h>

typedef __attribute__((ext_vector_type(8))) short bf16x8;
typedef __attribute__((ext_vector_type(4))) float f32x4;

__device__ __forceinline__ float leaky(float x) { return x > 0.0f ? x : 0.01f * x; }

__device__ __forceinline__ unsigned short f2b(float f) {
    unsigned u = __builtin_bit_cast(unsigned, f);
    u += 0x7fffu + ((u >> 16) & 1u);
    return (unsigned short)(u >> 16);
}

__device__ __forceinline__ bf16x8 cvt8(float4 u0, float4 u1) {
    bf16x8 r;
    r[0] = (short)f2b(u0.x); r[1] = (short)f2b(u0.y);
    r[2] = (short)f2b(u0.z); r[3] = (short)f2b(u0.w);
    r[4] = (short)f2b(u1.x); r[5] = (short)f2b(u1.y);
    r[6] = (short)f2b(u1.z); r[7] = (short)f2b(u1.w);
    return r;
}

// ================= D1: both HW means -> bf16 ; zero atomic-C region (R13-identical) =====
__global__ __launch_bounds__(256) void means_kernel(const float* __restrict__ xm,
                                                    const float* __restrict__ xd,
                                                    unsigned short* __restrict__ xm_b,
                                                    unsigned short* __restrict__ xd_b,
                                                    float4* __restrict__ zbase)
{
    int blk = blockIdx.x;
    int tid = threadIdx.x;
    if (blk >= 32768) {
        int idx = (blk - 32768) * 256 + tid;       // 641 blocks * 256 float4 = 656384 floats
        zbase[idx] = make_float4(0.f, 0.f, 0.f, 0.f);
        return;
    }
    if (blk < 16384) {
        int lane = tid & 63;
        int wid  = tid >> 6;
        int row  = blk * 4 + wid;                  // 0..65535
        const float4* r = (const float4*)(xm + (size_t)row * 784);
        float s = 0.0f;
        for (int i = lane; i < 196; i += 64) {
            float4 v = r[i];
            s += v.x + v.y + v.z + v.w;
        }
        #pragma unroll
        for (int off = 32; off; off >>= 1) s += __shfl_xor(s, off);
        if (lane == 0) xm_b[row] = f2b(s * (1.0f / 784.0f));
    } else {
        int b2  = blk - 16384;
        int sub = tid & 15;
        int r   = tid >> 4;
        int row = b2 * 16 + r;                     // 0..262143
        const float* base = xd + (size_t)row * 49;
        float s = base[sub] + base[sub + 16] + base[sub + 32];
        if (sub == 0) s += base[48];
        #pragma unroll
        for (int off = 8; off; off >>= 1) s += __shfl_xor(s, off);
        if (sub == 0) xd_b[row] = f2b(s * (1.0f / 49.0f));
    }
}

// ---------- gate / done (R10-validated) ----------
__device__ __forceinline__ void gate(const int* flag) {
    if (threadIdx.x == 0) {
        while (__hip_atomic_load(flag, __ATOMIC_RELAXED, __HIP_MEMORY_SCOPE_AGENT) == 0)
            __builtin_amdgcn_s_sleep(32);
    }
    __syncthreads();
    __builtin_amdgcn_fence(__ATOMIC_ACQUIRE, "agent");
}

__device__ __forceinline__ void done(int* cnt, int target, int* flag) {
    __syncthreads();
    if (threadIdx.x == 0) {
        asm volatile("s_waitcnt vmcnt(0)" ::: "memory");
        int old = __hip_atomic_fetch_add(cnt, 1, __ATOMIC_RELAXED, __HIP_MEMORY_SCOPE_AGENT);
        if (old == target - 1)
            __hip_atomic_store(flag, 1, __ATOMIC_RELAXED, __HIP_MEMORY_SCOPE_AGENT);
    }
}

// ================= shared GEMM phase (R6/R10-validated) =================
// C[m][n] += actA(A[m][k-slice]) @ B[n][k-slice]^T, atomic fp32 C; fp32 B staged to LDS as bf16.
__device__ __forceinline__ void gemm_phase(
    const void* __restrict__ A, int af, int aact,
    const float* __restrict__ B,
    float* __restrict__ C,
    int N, int K, int Kc, int k0, int n0,
    unsigned short (*Bs)[72], int tid)
{
    const int l  = tid & 63;
    const int lr = l & 15;
    const int lc = l >> 4;
    const int m0 = (tid >> 6) * 16;
    const int srow = tid >> 4;
    const int scol = (tid & 15) * 4;

    f32x4 acc0 = {0.f,0.f,0.f,0.f}, acc1 = {0.f,0.f,0.f,0.f};

    for (int kt = 0; kt < Kc; kt += 64) {
        float4 v = *(const float4*)(B + (size_t)(n0 + srow) * K + k0 + kt + scol);
        __syncthreads();
        Bs[srow][scol + 0] = f2b(v.x);
        Bs[srow][scol + 1] = f2b(v.y);
        Bs[srow][scol + 2] = f2b(v.z);
        Bs[srow][scol + 3] = f2b(v.w);
        __syncthreads();

        #pragma unroll
        for (int kc = 0; kc < 2; ++kc) {
            size_t aoff = (size_t)(m0 + lr) * K + k0 + kt + kc * 32 + lc * 8;
            bf16x8 a;
            if (!af) {
                a = *(const bf16x8*)((const unsigned short*)A + aoff);
            } else {
                const float* p = (const float*)A + aoff;
                float4 u0 = *(const float4*)p;
                float4 u1 = *(const float4*)(p + 4);
                if (aact) {
                    u0.x = leaky(u0.x); u0.y = leaky(u0.y);
                    u0.z = leaky(u0.z); u0.w = leaky(u0.w);
                    u1.x = leaky(u1.x); u1.y = leaky(u1.y);
                    u1.z = leaky(u1.z); u1.w = leaky(u1.w);
                }
                a = cvt8(u0, u1);
            }
            bf16x8 b0 = *(const bf16x8*)&Bs[lr][kc * 32 + lc * 8];
            bf16x8 b1 = *(const bf16x8*)&Bs[16 + lr][kc * 32 + lc * 8];
            acc0 = __builtin_amdgcn_mfma_f32_16x16x32_bf16(a, b0, acc0, 0, 0, 0);
            acc1 = __builtin_amdgcn_mfma_f32_16x16x32_bf16(a, b1, acc1, 0, 0, 0);
        }
    }

    #pragma unroll
    for (int r = 0; r < 4; ++r) {
        int m = m0 + lc * 4 + r;
        atomicAdd(&C[(size_t)m * N + n0 + lr],      acc0[r]);
        atomicAdd(&C[(size_t)m * N + n0 + 16 + lr], acc1[r]);
    }
}

// ================= D2: G1 || G2o (512 blocks, no gates) =================
// bid [0,256):   G1  C1 += xm_b @ wsh^T   (N=2048, K=512, S=4)
// bid [256,512): G2o C2o += xd_b @ ow1^T  (N=1024, K=2048, S=8)
__global__ __launch_bounds__(512) void d2_kernel(
    const unsigned short* __restrict__ xm_b, const unsigned short* __restrict__ xd_b,
    const float* __restrict__ wsh, const float* __restrict__ ow1,
    float* __restrict__ C1, float* __restrict__ C2o)
{
    __shared__ unsigned short Bs[32][72];
    const int bid = blockIdx.x, tid = threadIdx.x;
    if (bid < 256) {
        int nt = bid >> 2, s = bid & 3;
        gemm_phase(xm_b, 0, 0, wsh, C1, 2048, 512, 128, s * 128, nt * 32, Bs, tid);
    } else {
        int idx = bid - 256, nt = idx >> 3, s = idx & 7;
        gemm_phase(xd_b, 0, 0, ow1, C2o, 1024, 2048, 256, s * 256, nt * 32, Bs, tid);
    }
}

// ================= D3: fused G2s||G3o -> G3s -> tail (640 blocks, R10 topology) =========
// bid [0,256):   G2s C2s += C1 @ sw1^T             (N=1024,K=2048,S=8)  -> cntB/flagB
// bid [256,384): G3o C3o += leaky(C2o) @ ow2^T     (N=512,K=1024,S=8)   -> cntC/flagC@256
// bid [384,512): gate(B): G3s C3s += leaky(C2s) @ sw2^T                 -> cntC/flagC@256
// bid [512,640): gate(C): per-sample tail; last-arriving block finalizes.
__global__ __launch_bounds__(512, 4) void d3_kernel(
    float* __restrict__ wf,
    const float* __restrict__ sw1, const float* __restrict__ ow2, const float* __restrict__ ow3,
    const float* __restrict__ sw2, const float* __restrict__ sw3,
    const float* __restrict__ tw1, const float* __restrict__ tw2,
    const float* __restrict__ cw1, const float* __restrict__ cw2,
    const float* __restrict__ qw1, const float* __restrict__ qw2,
    const float* __restrict__ center, const float* __restrict__ proto,
    float* __restrict__ out)
{
    __shared__ unsigned short Bs[32][72];
    __shared__ float o2r[512], s2r[512];
    __shared__ float red[2][64][4];
    __shared__ float o3s[64], s3s[64], t1s[64], c1s[64], q1s[64];
    __shared__ float tmp[4][8];
    __shared__ int flag_sh;

    float* C1  = wf;                    // [128,2048]
    float* C2o = wf + 262144;           // [128,1024]
    float* C2s = wf + 393216;           // [128,1024]
    float* C3o = wf + 524288;           // [128,512]
    float* C3s = wf + 589824;           // [128,512]
    int*   cntB  = (int*)(wf + 655360);         // 128B-spaced lines, zeroed by D1
    int*   flagB = (int*)(wf + 655360 + 32);
    int*   cntC  = (int*)(wf + 655360 + 64);
    int*   flagC = (int*)(wf + 655360 + 96);
    int*   cntT  = (int*)(wf + 655360 + 128);
    float* ce_t = wf + 655616;          // [128] x4
    float* osv  = ce_t + 128;
    float* csv  = ce_t + 256;
    float* alv  = ce_t + 384;

    const int bid = blockIdx.x;
    const int tid = threadIdx.x;

    if (bid < 256) {
        int nt = bid >> 3, s = bid & 7;
        gemm_phase(C1, 1, 0, sw1, C2s, 1024, 2048, 256, s * 256, nt * 32, Bs, tid);
        done(cntB, 256, flagB);
        return;
    }
    if (bid < 384) {
        int idx = bid - 256, nt = idx >> 3, s = idx & 7;
        gemm_phase(C2o, 1, 1, ow2, C3o, 512, 1024, 128, s * 128, nt * 32, Bs, tid);
        done(cntC, 256, flagC);
        return;
    }
    if (bid < 512) {
        gate(flagB);
        int idx = bid - 384, nt = idx >> 3, s = idx & 7;
        gemm_phase(C2s, 1, 1, sw2, C3s, 512, 1024, 128, s * 128, nt * 32, Bs, tid);
        done(cntC, 256, flagC);
        return;
    }

    // ---------------- tail ----------------
    const int b = bid - 512;
    gate(flagC);

    {   // layer-2 activation (512 threads, 1 elem each path)
        int e = tid;
        o2r[e] = leaky(C3o[b * 512 + e]);
        s2r[e] = leaky(C3s[b * 512 + e]);
    }
    __syncthreads();
    {   // both layer-3 matvecs: p=path, o=output, q=K-quarter
        int p = tid >> 8, o = (tid >> 2) & 63, q = tid & 3;
        const float* wr = (p ? sw3 : ow3) + (size_t)o * 512 + q * 128;
        const float* xr = (p ? s2r : o2r) + q * 128;
        float acc = 0.f;
        for (int j = 0; j < 128; ++j) acc += wr[j] * xr[j];
        red[p][o][q] = acc;
    }
    __syncthreads();
    if (tid < 128) {
        int p = tid >> 6, o = tid & 63;
        float v = leaky(red[p][o][0] + red[p][o][1] + red[p][o][2] + red[p][o][3]);
        if (p) s3s[o] = v; else o3s[o] = v;
    }
    __syncthreads();

    float ce_val = 0.f;
    int o = tid;
    if (tid < 64) {
        float acc = 0.f;
        for (int j = 0; j < 64; ++j) acc += tw1[o * 128 + j] * s3s[j];
        for (int j = 0; j < 64; ++j) acc += tw1[o * 128 + 64 + j] * (s3s[j] - center[j]);
        t1s[o] = leaky(acc);
    }
    __syncthreads();
    if (tid < 64) {
        float acc = 0.f;
        for (int j = 0; j < 64; ++j) acc += tw2[o * 64 + j] * t1s[j];
        float tex = leaky(acc);
        float sim[4];
        #pragma unroll
        for (int k = 0; k < 4; ++k) {
            float d = tex - proto[k * 64 + o];
            float v = d * d;
            #pragma unroll
            for (int off = 32; off; off >>= 1) v += __shfl_xor(v, off);
            sim[k] = v;
        }
        int cat = 0; float best = sim[0];
        #pragma unroll
        for (int k = 1; k < 4; ++k) if (sim[k] > best) { best = sim[k]; cat = k; }
        float sume = 0.f;
        #pragma unroll
        for (int k = 0; k < 4; ++k) sume += expf(sim[k] - best);
        ce_val = logf(sume);
        float acc2 = 0.f;
        for (int j = 0; j < 64; ++j) acc2 += cw1[o * 128 + j] * o3s[j];
        for (int j = 0; j < 64; ++j) acc2 += cw1[o * 128 + 64 + j] * (o3s[j] - proto[cat * 64 + j]);
        c1s[o] = leaky(acc2);
        acc2 = 0.f;
        for (int j = 0; j < 64; ++j) acc2 += qw1[o * 64 + j] * o3s[j];
        q1s[o] = leaky(acc2);
    }
    __syncthreads();
    if (tid < 64) {
        float acc = 0.f;
        for (int j = 0; j < 64; ++j) acc += cw2[o * 64 + j] * c1s[j];
        float cf = leaky(acc);
        float dc = cf - center[o];
        float cs = dc * dc;
        #pragma unroll
        for (int off = 32; off; off >>= 1) cs += __shfl_xor(cs, off);
        acc = 0.f;
        for (int j = 0; j < 64; ++j) acc += qw2[o * 64 + j] * q1s[j];
        float qf = leaky(acc);
        float dq = qf - center[o];
        float os = dq * dq;
        #pragma unroll
        for (int off = 32; off; off >>= 1) os += __shfl_xor(os, off);
        if (o == 0) {
            __hip_atomic_store(&ce_t[b], ce_val, __ATOMIC_RELAXED, __HIP_MEMORY_SCOPE_AGENT);
            __hip_atomic_store(&osv[b],  os,     __ATOMIC_RELAXED, __HIP_MEMORY_SCOPE_AGENT);
            __hip_atomic_store(&csv[b],  cs,     __ATOMIC_RELAXED, __HIP_MEMORY_SCOPE_AGENT);
            __hip_atomic_store(&alv[b],  fabsf(os - cs), __ATOMIC_RELAXED, __HIP_MEMORY_SCOPE_AGENT);
        }
    }
    __syncthreads();
    if (tid == 0) {
        asm volatile("s_waitcnt vmcnt(0)" ::: "memory");
        int old = __hip_atomic_fetch_add(cntT, 1, __ATOMIC_ACQ_REL, __HIP_MEMORY_SCOPE_AGENT);
        flag_sh = (old == 127);
    }
    __syncthreads();
    if (flag_sh) {
        float v0 = 0.f, v1 = 0.f, v2 = 0.f, v3 = 0.f;
        if (tid < 128) {
            v0 = __hip_atomic_load(&ce_t[tid], __ATOMIC_RELAXED, __HIP_MEMORY_SCOPE_AGENT);
            v1 = __hip_atomic_load(&osv[tid],  __ATOMIC_RELAXED, __HIP_MEMORY_SCOPE_AGENT);
            v2 = __hip_atomic_load(&csv[tid],  __ATOMIC_RELAXED, __HIP_MEMORY_SCOPE_AGENT);
            v3 = __hip_atomic_load(&alv[tid],  __ATOMIC_RELAXED, __HIP_MEMORY_SCOPE_AGENT);
        }
        float v[4] = { v0, v1, v2, v3 };
        int lane = tid & 63, wv = tid >> 6;
        #pragma unroll
        for (int i = 0; i < 4; ++i) {
            float x = v[i];
            #pragma unroll
            for (int off = 32; off; off >>= 1) x += __shfl_xor(x, off);
            if (lane == 0) tmp[i][wv] = x;
        }
        __syncthreads();
        if (tid < 4) {
            float s = 0.f;
            #pragma unroll
            for (int j = 0; j < 8; ++j) s += tmp[tid][j];
            out[tid] = s * (1.0f / 128.0f);
        }
    }
}

// ================= launcher =================
extern "C" void kernel_launch(void* const* d_in, const int* in_sizes, int n_in,
                              void* d_out, int out_size, void* d_ws, size_t ws_size,
                              hipStream_t stream)
{
    const float* x_mid     = (const float*)d_in[0];
    const float* x_deep    = (const float*)d_in[1];
    const float* w_shallow = (const float*)d_in[2];
    const float* ow1 = (const float*)d_in[3];
    const float* ow2 = (const float*)d_in[4];
    const float* ow3 = (const float*)d_in[5];
    const float* sw1 = (const float*)d_in[6];
    const float* sw2 = (const float*)d_in[7];
    const float* sw3 = (const float*)d_in[8];
    const float* tw1 = (const float*)d_in[9];
    const float* tw2 = (const float*)d_in[10];
    const float* cw1 = (const float*)d_in[11];
    const float* cw2 = (const float*)d_in[12];
    const float* qw1 = (const float*)d_in[13];
    const float* qw2 = (const float*)d_in[14];
    const float* center = (const float*)d_in[15];
    const float* proto  = (const float*)d_in[16];
    float* out = (float*)d_out;

    float* wf = (float*)d_ws;
    // zero region: wf[0 .. 656384)
    unsigned short* xm_b = (unsigned short*)(wf + 656384);            // [128,512]
    unsigned short* xd_b = xm_b + 65536;                              // [128,2048]
    float* C1  = wf;
    float* C2o = wf + 262144;

    // D1: means + zero
    means_kernel<<<33409, 256, 0, stream>>>(x_mid, x_deep, xm_b, xd_b, (float4*)wf);

    // D2: G1 || G2o (512 blocks, no gates)
    d2_kernel<<<512, 512, 0, stream>>>(xm_b, xd_b, w_shallow, ow1, C1, C2o);

    // D3: fused G2s||G3o -> G3s -> tail (640 blocks, R10-regime gating)
    d3_kernel<<<640, 512, 0, stream>>>(wf, sw1, ow2, ow3, sw2, sw3,
                                       tw1, tw2, cw1, cw2, qw1, qw2,
                                       center, proto, out);
}